// Round 17
// baseline (113.284 us; speedup 1.0000x reference)
//
#include <hip/hip_runtime.h>
#include <hip/hip_bf16.h>

#define NND 300000
#define RR 1200
#define KADJ 20
#define BB 256
#define MM 50
#define DD 100
#define ROWS (BB*MM*KADJ)   // 256000
#define MKJ (MM*KADJ)       // 1000
#define N1P 208
#define K1S 8               // layer-1 packed K = 256 (0..3 node, 4..7 rel)
#define NT1 7
#define NT2 7
#define K2S 4
#define H1S 136             // H1 row stride in shorts

typedef __attribute__((ext_vector_type(8))) short short8;
typedef __attribute__((ext_vector_type(4))) float f32x4;

__device__ inline unsigned short f2bf(float f) {
  union { float f; unsigned u; } v; v.f = f;
  return (unsigned short)((v.u + 0x7FFFu + ((v.u >> 16) & 1u)) >> 16);
}
__device__ inline unsigned pkbf2(float x, float y) {
  __hip_bfloat162 p = __float22bfloat162_rn(make_float2(x, y));
  unsigned u; __builtin_memcpy(&u, &p, 4); return u;
}
__device__ inline float fast_tanh(float x) {
  float e = __builtin_amdgcn_exp2f(x * 2.885390082f);
  float r = __builtin_amdgcn_rcpf(e + 1.f);
  return __builtin_fmaf(-2.f, r, 1.f);
}
__device__ inline float fast_sigmoid(float x) {
  float e = __builtin_amdgcn_exp2f(x * -1.442695041f);
  return __builtin_amdgcn_rcpf(1.f + e);
}

// ---------------- prep: packed weight fragments + G1 table ----------------
__global__ __launch_bounds__(256) void k_prep(
    const float* __restrict__ gemb,
    const float* __restrict__ aw1, const float* __restrict__ ab1,
    const float* __restrict__ cw1, const float* __restrict__ cb1,
    const float* __restrict__ aw2, const float* __restrict__ cw2,
    short* __restrict__ wf1, short* __restrict__ wf2, float* __restrict__ G1) {
  int t = blockIdx.x * blockDim.x + threadIdx.x;
  if (t < 57344) {  // wf1: 2h*7nt*8ks*64*8
    int j = t & 7, l = (t >> 3) & 63, f = t >> 9;
    int ks = f & 7, r2 = f >> 3;
    int nt = r2 % 7, h = r2 / 7;
    int kp = ks * 32 + ((l >> 4) * 8) + j;
    int n = nt * 16 + (l & 15);
    float v = 0.f;
    if (n < DD) {
      const float* w1 = h ? cw1 : aw1;
      if (kp < DD) v = w1[(DD + kp) * DD + n];
      else if (kp >= 128 && kp < 228) v = w1[(200 + kp - 128) * DD + n];
    }
    wf1[t] = (short)f2bf(v);
    return;
  }
  int t2 = t - 57344;
  if (t2 < 28672) {  // wf2
    int j = t2 & 7, l = (t2 >> 3) & 63, f = t2 >> 9;
    int ks = f & 3, r2 = f >> 2;
    int nt = r2 % 7, h = r2 / 7;
    int k = ks * 32 + ((l >> 4) * 8) + j;
    int n = nt * 16 + (l & 15);
    float v = 0.f;
    if (k < DD && n < DD) v = (h ? cw2 : aw2)[k * DD + n];
    wf2[t2] = (short)f2bf(v);
    return;
  }
  int t3 = t2 - 28672;
  if (t3 < BB * N1P) {  // G1
    int b = t3 / N1P, n = t3 % N1P;
    float acc = 0.f;
    if (n < 200) {
      const float* w1 = (n < DD) ? aw1 : cw1;
      const float* b1 = (n < DD) ? ab1 : cb1;
      int jj = (n < DD) ? n : n - DD;
      acc = b1[jj];
      for (int d = 0; d < DD; ++d) acc += gemb[b * DD + d] * w1[d * DD + jj];
    }
    G1[t3] = acc;
  }
}

// ---------------- softmax over raw dots (in place in outDR) ----------------
__global__ __launch_bounds__(256) void k_soft(float* __restrict__ dr) {
  __shared__ float red[4];
  int b = blockIdx.x, tid = threadIdx.x;
  int lane = tid & 63, w = tid >> 6;
  float* p = dr + (size_t)b * MKJ;
  float v[4], mx = -1e30f;
  #pragma unroll
  for (int i = 0; i < 4; ++i) {
    int j = tid + i * 256;
    v[i] = (j < MKJ) ? p[j] : -1e30f;
    mx = fmaxf(mx, v[i]);
  }
  #pragma unroll
  for (int off = 32; off; off >>= 1) mx = fmaxf(mx, __shfl_xor(mx, off, 64));
  if (lane == 0) red[w] = mx;
  __syncthreads();
  mx = fmaxf(fmaxf(red[0], red[1]), fmaxf(red[2], red[3]));
  float e[4], se = 0.f;
  #pragma unroll
  for (int i = 0; i < 4; ++i) {
    e[i] = __expf(v[i] - mx);
    if (tid + i * 256 < MKJ) se += e[i];
  }
  #pragma unroll
  for (int off = 32; off; off >>= 1) se += __shfl_xor(se, off, 64);
  __syncthreads();
  if (lane == 0) red[w] = se;
  __syncthreads();
  se = red[0] + red[1] + red[2] + red[3];
  float inv = 1.f / se;
  #pragma unroll
  for (int i = 0; i < 4; ++i) {
    int j = tid + i * 256;
    if (j < MKJ) p[j] = e[i] * inv;
  }
}

// ---------------- k_all: 512 thr / 128 rows; single-buffer WB; 3 blocks/CU ----------------
template<bool FUSE>
__global__ __launch_bounds__(512, 4) void k_all(
    const float* __restrict__ nemb, const float* __restrict__ remb,
    const float* __restrict__ oemb, const float* __restrict__ gemb,
    const int* __restrict__ eadj, const int* __restrict__ radj,
    const int* __restrict__ nodes,
    const short* __restrict__ wf1, const short* __restrict__ wf2,
    const float* __restrict__ G1,
    const float* __restrict__ ab2, const float* __restrict__ cb2,
    const float* __restrict__ aw3, const float* __restrict__ ab3,
    const float* __restrict__ cw3, const float* __restrict__ cb3,
    float* __restrict__ outA, float* __restrict__ outQ,
    float* __restrict__ dots, float* __restrict__ outNG) {
  __shared__ uint4 WB[512];                   // 8 KB weight buffer (single)
  __shared__ unsigned short H1[128 * H1S];    // 34.8 KB (NG staging, then layer-1 acts)
  __shared__ float G1s[224], b2s[224], w3s[224];
  __shared__ float gs[128], os[128];          // padded (cols>=100 are 0)
  __shared__ int nidS[128], ridS[128];

  int hid = blockIdx.x;        // 2048
  int x = hid & 7, b = hid >> 3;
  int tid = threadIdx.x;
  int lane = tid & 63, w = tid >> 6, ln = lane & 15, lg = lane >> 4;

  if (tid < 128) {
    int row = x * 128 + tid;
    int rc = row < MKJ ? row : MKJ - 1;
    int m = rc / KADJ, kk = rc - m * KADJ;
    int v = nodes[b * MM + m];
    nidS[tid] = eadj[v * KADJ + kk];
    ridS[tid] = radj[v * KADJ + kk];
  }
  for (int i = tid; i < 224; i += 512) {
    int h = i / 112, n = i - h * 112;
    G1s[i] = (n < DD) ? G1[b * N1P + h * DD + n] : 0.f;
    b2s[i] = (n < DD) ? (h ? cb2[n] : ab2[n]) : 0.f;
    w3s[i] = (n < DD) ? (h ? cw3[n] : aw3[n]) : 0.f;
  }
  if (FUSE) {
    for (int i = tid; i < 128; i += 512) {
      gs[i] = (i < DD) ? gemb[b * DD + i] : 0.f;
      os[i] = (i < DD) ? oemb[b * DD + i] : 0.f;
    }
  }
  __syncthreads();

  // ---- the ONLY nemb gather: a1 fragments (node + rel); f32 dot partial ----
  short8 a1[8];
  int myrow = w * 16 + ln;              // 0..127
  int grow = x * 128 + myrow;
  bool vrow = grow < MKJ;
  float pp = 0.f;
  {
    const float* nrow = nemb + (size_t)nidS[myrow] * DD;
    const float* rrow = remb + (size_t)ridS[myrow] * DD;
    #pragma unroll
    for (int ks = 0; ks < 8; ++ks) {
      const float* src = (ks < 4) ? nrow : rrow;
      int cb = (ks & 3) * 32 + lg * 8;
      float4 lo = make_float4(0.f,0.f,0.f,0.f), hi = lo;
      if (cb <= 96) lo = *(const float4*)(src + cb);
      if (cb + 4 <= 96) hi = *(const float4*)(src + cb + 4);
      union { short8 s; unsigned u[4]; } fr;
      fr.u[0] = pkbf2(lo.x, lo.y); fr.u[1] = pkbf2(lo.z, lo.w);
      fr.u[2] = pkbf2(hi.x, hi.y); fr.u[3] = pkbf2(hi.z, hi.w);
      a1[ks] = fr.s;
      if (FUSE && ks < 4 && cb <= 96) {
        pp += os[cb+0]*(lo.x+gs[cb+0]) + os[cb+1]*(lo.y+gs[cb+1]) +
              os[cb+2]*(lo.z+gs[cb+2]) + os[cb+3]*(lo.w+gs[cb+3]);
        if (cb + 4 <= 96)
          pp += os[cb+4]*(hi.x+gs[cb+4]) + os[cb+5]*(hi.y+gs[cb+5]) +
                os[cb+6]*(hi.z+gs[cb+6]) + os[cb+7]*(hi.w+gs[cb+7]);
      }
    }
  }

  // early prefetch of layer-1 head-0 nt=0 tile (8 KB = 512 x uint4)
  uint4 p0 = ((const uint4*)wf1)[tid];

  if (FUSE) {
    // dots (f32-accurate)
    pp += __shfl_xor(pp, 16, 64);
    pp += __shfl_xor(pp, 32, 64);
    if (lg == 0 && vrow) dots[(size_t)b * MKJ + grow] = pp;

    // stage node bf16 into H1 (XOR-swizzled 16-B granules)
    #pragma unroll
    for (int ks = 0; ks < 4; ++ks) {
      int col = (ks * 32 + lg * 8) ^ ((myrow & 7) << 3);
      *(short8*)&H1[myrow * H1S + col] = a1[ks];
    }
    __syncthreads();

    // dense NG store: 128 rows x 400B contiguous slab, every sector written once
    const size_t ngbase = ((size_t)b * MKJ + (size_t)x * 128) * DD;
    for (int q = tid; q < 3200; q += 512) {
      int fidx = q * 4;
      int row = fidx / DD;          // 0..127 (100 % 4 == 0 -> no row crossing)
      int col = fidx - row * DD;
      if (x * 128 + row < MKJ) {
        int sc = ((col & ~7) ^ ((row & 7) << 3)) + (col & 7);
        unsigned long long d = *(const unsigned long long*)&H1[row * H1S + sc];
        f32x4 t;
        #pragma unroll
        for (int e = 0; e < 4; ++e) {
          unsigned u = (unsigned)((d >> (16 * e)) & 0xFFFFull) << 16;
          float v; __builtin_memcpy(&v, &u, 4);
          t[e] = v + gs[col + e];
        }
        __builtin_nontemporal_store(t, (f32x4*)(outNG + ngbase + fidx));
      }
    }
    __syncthreads();   // H1 fully consumed before layer-1 overwrites it
  }

  float b3v[2] = {ab3[0], cb3[0]};
  float* outs[2] = {outA, outQ};

  for (int h = 0; h < 2; ++h) {
    // ======== layer 1: 8 KB/nt tiles, single-buffer + reg prefetch ========
    const char* wf1b = (const char*)wf1 + (size_t)h * 57344;
    if (h == 0) {
      WB[tid] = p0;
    } else {
      __syncthreads();
      WB[tid] = ((const uint4*)wf1b)[tid];
    }
    __syncthreads();
    for (int nt = 0; nt < NT1; ++nt) {
      uint4 s0;
      if (nt < NT1 - 1)
        s0 = ((const uint4*)(wf1b + (size_t)(nt + 1) * 8192))[tid];
      int n = nt * 16 + ln;
      float g = G1s[h * 112 + n];
      f32x4 acc = {g, g, g, g};
      #pragma unroll
      for (int ks = 0; ks < K1S; ++ks) {
        short8 bw = *(const short8*)&WB[ks * 64 + lane];
        acc = __builtin_amdgcn_mfma_f32_16x16x32_bf16(a1[ks], bw, acc, 0, 0, 0);
      }
      if (n < DD) {
        #pragma unroll
        for (int r = 0; r < 4; ++r)
          H1[(w * 16 + lg * 4 + r) * H1S + n] = f2bf(fast_tanh(acc[r]));
      }
      if (nt < NT1 - 1) {
        __syncthreads();          // all waves done reading WB
        WB[tid] = s0;
        __syncthreads();          // new tile visible
      }
    }
    __syncthreads();              // last-tile reads + H1 writes done

    // a2 fragments from own wave's H1 rows; zero K-pad cols (>=100) in-register
    short8 a2[4];
    #pragma unroll
    for (int ks = 0; ks < K2S; ++ks)
      a2[ks] = *(const short8*)&H1[myrow * H1S + ks * 32 + lg * 8];
    {
      union { short8 s; unsigned short us[8]; } m; m.s = a2[3];
      int cb = 96 + lg * 8;
      #pragma unroll
      for (int q = 0; q < 8; ++q) if (cb + q >= DD) m.us[q] = 0;
      a2[3] = m.s;
    }

    // ======== layer 2+3: 4 KB/nt tiles, single-buffer + reg prefetch ========
    const char* wf2b = (const char*)wf2 + (size_t)h * 28672;
    if (tid < 256) WB[tid] = ((const uint4*)wf2b)[tid];
    __syncthreads();
    float part[4] = {0.f, 0.f, 0.f, 0.f};
    for (int nt = 0; nt < NT2; ++nt) {
      uint4 s0;
      if (nt < NT2 - 1 && tid < 256)
        s0 = ((const uint4*)(wf2b + (size_t)(nt + 1) * 4096))[tid];
      f32x4 acc = {0.f, 0.f, 0.f, 0.f};
      #pragma unroll
      for (int ks = 0; ks < K2S; ++ks) {
        short8 bw = *(const short8*)&WB[ks * 64 + lane];
        acc = __builtin_amdgcn_mfma_f32_16x16x32_bf16(a2[ks], bw, acc, 0, 0, 0);
      }
      int n = nt * 16 + ln;
      float b2v = b2s[h * 112 + n];
      float w3v = w3s[h * 112 + n];
      #pragma unroll
      for (int r = 0; r < 4; ++r)
        part[r] += fast_tanh(acc[r] + b2v) * w3v;
      if (nt < NT2 - 1) {
        __syncthreads();
        if (tid < 256) WB[tid] = s0;
        __syncthreads();
      }
    }
    #pragma unroll
    for (int r = 0; r < 4; ++r) {
      float s = part[r];
      s += __shfl_xor(s, 1, 64); s += __shfl_xor(s, 2, 64);
      s += __shfl_xor(s, 4, 64); s += __shfl_xor(s, 8, 64);
      if (ln == 0) {
        int row = x * 128 + w * 16 + lg * 4 + r;
        if (row < MKJ) outs[h][(size_t)b * MKJ + row] = fast_sigmoid(s + b3v[h]);
      }
    }
    __syncthreads();   // before next head restages WB / H1
  }
}

// ---------------- fallback rewards (non-fused path; full softmax inside) ----------------
__global__ __launch_bounds__(1024) void k_rewards(
    const float* __restrict__ nemb, const float* __restrict__ oemb,
    const float* __restrict__ gemb,
    const int* __restrict__ eadj, const int* __restrict__ nodes,
    float* __restrict__ outDR, float* __restrict__ outNG) {
  __shared__ float dots[MKJ];
  __shared__ float red[16];
  int b = blockIdx.x;
  int tid = threadIdx.x;
  int lane = tid & 63, w = tid >> 6;
  int d1 = lane + 64;
  float o0 = oemb[b * DD + lane];
  float g0 = gemb[b * DD + lane];
  float o1 = (d1 < DD) ? oemb[b * DD + d1] : 0.f;
  float g1 = (d1 < DD) ? gemb[b * DD + d1] : 0.f;
  for (int j = w; j < MKJ; j += 16) {
    int m = j / KADJ, kk = j - m * KADJ;
    int v = nodes[b * MM + m];
    int nid = eadj[v * KADJ + kk];
    const float* nr = nemb + (size_t)nid * DD;
    float s0 = g0 + nr[lane];
    float s1 = (d1 < DD) ? (g1 + nr[d1]) : 0.f;
    float* ngr = outNG + ((long long)b * MKJ + j) * DD;
    ngr[lane] = s0;
    if (d1 < DD) ngr[d1] = s1;
    float p = o0 * s0 + o1 * s1;
    p += __shfl_xor(p, 1, 64); p += __shfl_xor(p, 2, 64); p += __shfl_xor(p, 4, 64);
    p += __shfl_xor(p, 8, 64); p += __shfl_xor(p, 16, 64); p += __shfl_xor(p, 32, 64);
    if (lane == 0) dots[j] = p;
  }
  __syncthreads();
  float mx = -1e30f;
  for (int j = tid; j < MKJ; j += 1024) mx = fmaxf(mx, dots[j]);
  for (int off = 32; off; off >>= 1) mx = fmaxf(mx, __shfl_xor(mx, off, 64));
  if (lane == 0) red[w] = mx;
  __syncthreads();
  mx = red[0];
  #pragma unroll
  for (int i = 1; i < 16; ++i) mx = fmaxf(mx, red[i]);
  float se = 0.f;
  for (int j = tid; j < MKJ; j += 1024) se += __expf(dots[j] - mx);
  for (int off = 32; off; off >>= 1) se += __shfl_xor(se, off, 64);
  __syncthreads();
  if (lane == 0) red[w] = se;
  __syncthreads();
  se = 0.f;
  #pragma unroll
  for (int i = 0; i < 16; ++i) se += red[i];
  float inv = 1.f / se;
  for (int j = tid; j < MKJ; j += 1024) outDR[b * MKJ + j] = __expf(dots[j] - mx) * inv;
}

extern "C" void kernel_launch(void* const* d_in, const int* in_sizes, int n_in,
                              void* d_out, int out_size, void* d_ws, size_t ws_size,
                              hipStream_t stream) {
  const float* nemb = (const float*)d_in[0];
  const float* remb = (const float*)d_in[1];
  const float* oemb = (const float*)d_in[2];
  const float* gemb = (const float*)d_in[3];
  const float* aw1 = (const float*)d_in[4];
  const float* ab1 = (const float*)d_in[5];
  const float* aw2 = (const float*)d_in[6];
  const float* ab2 = (const float*)d_in[7];
  const float* aw3 = (const float*)d_in[8];
  const float* ab3 = (const float*)d_in[9];
  const float* cw1 = (const float*)d_in[10];
  const float* cb1 = (const float*)d_in[11];
  const float* cw2 = (const float*)d_in[12];
  const float* cb2 = (const float*)d_in[13];
  const float* cw3 = (const float*)d_in[14];
  const float* cb3 = (const float*)d_in[15];
  const int* eadj = (const int*)d_in[16];
  const int* radj = (const int*)d_in[17];
  const int* nodes = (const int*)d_in[18];

  float* out = (float*)d_out;
  float* outA = out;
  float* outQ = out + ROWS;
  float* outDR = out + 2 * ROWS;
  float* outNG = out + 3 * ROWS;

  // scratch: wf1 114,688 B | wf2 57,344 B | G1 212,992 B = 385,024 B
  const size_t need = 385024;
  bool fuse = ws_size >= need;
  char* scratch = (char*)d_ws;
  if (!fuse) {
    scratch = (char*)(out + ((size_t)3 * ROWS + (size_t)ROWS * DD - need / 4));
  }
  short* wf1 = (short*)scratch;
  short* wf2 = (short*)(scratch + 114688);
  float* G1 = (float*)(scratch + 172032);

  k_prep<<<544, 256, 0, stream>>>(gemb, aw1, ab1, cw1, cb1, aw2, cw2, wf1, wf2, G1);
  if (fuse) {
    k_all<true><<<2048, 512, 0, stream>>>(nemb, remb, oemb, gemb, eadj, radj, nodes,
                                          wf1, wf2, G1, ab2, cb2, aw3, ab3, cw3, cb3,
                                          outA, outQ, outDR, outNG);
    k_soft<<<BB, 256, 0, stream>>>(outDR);
  } else {
    k_all<false><<<2048, 512, 0, stream>>>(nemb, remb, oemb, gemb, eadj, radj, nodes,
                                           wf1, wf2, G1, ab2, cb2, aw3, ab3, cw3, cb3,
                                           outA, outQ, outDR, outNG);
    k_rewards<<<BB, 1024, 0, stream>>>(nemb, oemb, gemb, eadj, nodes, outDR, outNG);
  }
}

// Round 18
// 109.858 us; speedup vs baseline: 1.0312x; 1.0312x over previous
//
#include <hip/hip_runtime.h>
#include <hip/hip_bf16.h>

#define NND 300000
#define RR 1200
#define KADJ 20
#define BB 256
#define MM 50
#define DD 100
#define ROWS (BB*MM*KADJ)   // 256000
#define MKJ (MM*KADJ)       // 1000
#define N1P 208
#define K1S 8               // layer-1 packed K = 256 (0..3 node, 4..7 rel)
#define NT1 7
#define NT2 7
#define K2S 4
#define H1S 136             // H1 row stride in shorts

typedef __attribute__((ext_vector_type(8))) short short8;
typedef __attribute__((ext_vector_type(4))) float f32x4;

__device__ inline unsigned short f2bf(float f) {
  union { float f; unsigned u; } v; v.f = f;
  return (unsigned short)((v.u + 0x7FFFu + ((v.u >> 16) & 1u)) >> 16);
}
__device__ inline unsigned pkbf2(float x, float y) {
  __hip_bfloat162 p = __float22bfloat162_rn(make_float2(x, y));
  unsigned u; __builtin_memcpy(&u, &p, 4); return u;
}
__device__ inline float fast_tanh(float x) {
  float e = __builtin_amdgcn_exp2f(x * 2.885390082f);
  float r = __builtin_amdgcn_rcpf(e + 1.f);
  return __builtin_fmaf(-2.f, r, 1.f);
}
__device__ inline float fast_sigmoid(float x) {
  float e = __builtin_amdgcn_exp2f(x * -1.442695041f);
  return __builtin_amdgcn_rcpf(1.f + e);
}

// ---------------- prep: packed weight fragments + G1 table ----------------
__global__ __launch_bounds__(256) void k_prep(
    const float* __restrict__ gemb,
    const float* __restrict__ aw1, const float* __restrict__ ab1,
    const float* __restrict__ cw1, const float* __restrict__ cb1,
    const float* __restrict__ aw2, const float* __restrict__ cw2,
    short* __restrict__ wf1, short* __restrict__ wf2, float* __restrict__ G1) {
  int t = blockIdx.x * blockDim.x + threadIdx.x;
  if (t < 57344) {  // wf1: 2h*7nt*8ks*64*8
    int j = t & 7, l = (t >> 3) & 63, f = t >> 9;
    int ks = f & 7, r2 = f >> 3;
    int nt = r2 % 7, h = r2 / 7;
    int kp = ks * 32 + ((l >> 4) * 8) + j;
    int n = nt * 16 + (l & 15);
    float v = 0.f;
    if (n < DD) {
      const float* w1 = h ? cw1 : aw1;
      if (kp < DD) v = w1[(DD + kp) * DD + n];
      else if (kp >= 128 && kp < 228) v = w1[(200 + kp - 128) * DD + n];
    }
    wf1[t] = (short)f2bf(v);
    return;
  }
  int t2 = t - 57344;
  if (t2 < 28672) {  // wf2
    int j = t2 & 7, l = (t2 >> 3) & 63, f = t2 >> 9;
    int ks = f & 3, r2 = f >> 2;
    int nt = r2 % 7, h = r2 / 7;
    int k = ks * 32 + ((l >> 4) * 8) + j;
    int n = nt * 16 + (l & 15);
    float v = 0.f;
    if (k < DD && n < DD) v = (h ? cw2 : aw2)[k * DD + n];
    wf2[t2] = (short)f2bf(v);
    return;
  }
  int t3 = t2 - 28672;
  if (t3 < BB * N1P) {  // G1
    int b = t3 / N1P, n = t3 % N1P;
    float acc = 0.f;
    if (n < 200) {
      const float* w1 = (n < DD) ? aw1 : cw1;
      const float* b1 = (n < DD) ? ab1 : cb1;
      int jj = (n < DD) ? n : n - DD;
      acc = b1[jj];
      for (int d = 0; d < DD; ++d) acc += gemb[b * DD + d] * w1[d * DD + jj];
    }
    G1[t3] = acc;
  }
}

// ---------------- softmax over raw dots (in place in outDR) ----------------
__global__ __launch_bounds__(256) void k_soft(float* __restrict__ dr) {
  __shared__ float red[4];
  int b = blockIdx.x, tid = threadIdx.x;
  int lane = tid & 63, w = tid >> 6;
  float* p = dr + (size_t)b * MKJ;
  float v[4], mx = -1e30f;
  #pragma unroll
  for (int i = 0; i < 4; ++i) {
    int j = tid + i * 256;
    v[i] = (j < MKJ) ? p[j] : -1e30f;
    mx = fmaxf(mx, v[i]);
  }
  #pragma unroll
  for (int off = 32; off; off >>= 1) mx = fmaxf(mx, __shfl_xor(mx, off, 64));
  if (lane == 0) red[w] = mx;
  __syncthreads();
  mx = fmaxf(fmaxf(red[0], red[1]), fmaxf(red[2], red[3]));
  float e[4], se = 0.f;
  #pragma unroll
  for (int i = 0; i < 4; ++i) {
    e[i] = __expf(v[i] - mx);
    if (tid + i * 256 < MKJ) se += e[i];
  }
  #pragma unroll
  for (int off = 32; off; off >>= 1) se += __shfl_xor(se, off, 64);
  __syncthreads();
  if (lane == 0) red[w] = se;
  __syncthreads();
  se = red[0] + red[1] + red[2] + red[3];
  float inv = 1.f / se;
  #pragma unroll
  for (int i = 0; i < 4; ++i) {
    int j = tid + i * 256;
    if (j < MKJ) p[j] = e[i] * inv;
  }
}

// ---------------- k_all: gather -> dots -> MLP; NG generated LAST (no drain stall) ----------------
template<bool FUSE>
__global__ __launch_bounds__(256, 4) void k_all(
    const float* __restrict__ nemb, const float* __restrict__ remb,
    const float* __restrict__ oemb, const float* __restrict__ gemb,
    const int* __restrict__ eadj, const int* __restrict__ radj,
    const int* __restrict__ nodes,
    const short* __restrict__ wf1, const short* __restrict__ wf2,
    const float* __restrict__ G1,
    const float* __restrict__ ab2, const float* __restrict__ cb2,
    const float* __restrict__ aw3, const float* __restrict__ ab3,
    const float* __restrict__ cw3, const float* __restrict__ cb3,
    float* __restrict__ outA, float* __restrict__ outQ,
    float* __restrict__ dots, float* __restrict__ outNG) {
  __shared__ uint4 WB[2][512];               // 16 KB weight double-buffer
  __shared__ unsigned short H1[64 * H1S];    // 17.4 KB (layer-1 acts, then NG staging)
  __shared__ float G1s[224], b2s[224], w3s[224];
  __shared__ float gs[128], os[128];         // padded (cols>=100 are 0)
  __shared__ int nidS[64], ridS[64];

  int hid = blockIdx.x;        // 4096
  int x = hid & 15, b = hid >> 4;
  int tid = threadIdx.x;
  int lane = tid & 63, w = tid >> 6, ln = lane & 15, lg = lane >> 4;

  if (tid < 64) {
    int row = x * 64 + tid;
    int rc = row < MKJ ? row : MKJ - 1;
    int m = rc / KADJ, kk = rc - m * KADJ;
    int v = nodes[b * MM + m];
    nidS[tid] = eadj[v * KADJ + kk];
    ridS[tid] = radj[v * KADJ + kk];
  }
  for (int i = tid; i < 224; i += 256) {
    int h = i / 112, n = i - h * 112;
    G1s[i] = (n < DD) ? G1[b * N1P + h * DD + n] : 0.f;
    b2s[i] = (n < DD) ? (h ? cb2[n] : ab2[n]) : 0.f;
    w3s[i] = (n < DD) ? (h ? cw3[n] : aw3[n]) : 0.f;
  }
  if (FUSE) {
    for (int i = tid; i < 128; i += 256) {
      gs[i] = (i < DD) ? gemb[b * DD + i] : 0.f;
      os[i] = (i < DD) ? oemb[b * DD + i] : 0.f;
    }
  }
  __syncthreads();

  // ---- the ONLY nemb gather: a1 fragments (node + rel); f32 dot partial ----
  short8 a1[8];
  int myrow = w * 16 + ln;
  int grow = x * 64 + myrow;
  bool vrow = grow < MKJ;
  float pp = 0.f;
  {
    const float* nrow = nemb + (size_t)nidS[myrow] * DD;
    const float* rrow = remb + (size_t)ridS[myrow] * DD;
    #pragma unroll
    for (int ks = 0; ks < 8; ++ks) {
      const float* src = (ks < 4) ? nrow : rrow;
      int cb = (ks & 3) * 32 + lg * 8;
      float4 lo = make_float4(0.f,0.f,0.f,0.f), hi = lo;
      if (cb <= 96) lo = *(const float4*)(src + cb);
      if (cb + 4 <= 96) hi = *(const float4*)(src + cb + 4);
      union { short8 s; unsigned u[4]; } fr;
      fr.u[0] = pkbf2(lo.x, lo.y); fr.u[1] = pkbf2(lo.z, lo.w);
      fr.u[2] = pkbf2(hi.x, hi.y); fr.u[3] = pkbf2(hi.z, hi.w);
      a1[ks] = fr.s;
      if (FUSE && ks < 4 && cb <= 96) {
        pp += os[cb+0]*(lo.x+gs[cb+0]) + os[cb+1]*(lo.y+gs[cb+1]) +
              os[cb+2]*(lo.z+gs[cb+2]) + os[cb+3]*(lo.w+gs[cb+3]);
        if (cb + 4 <= 96)
          pp += os[cb+4]*(hi.x+gs[cb+4]) + os[cb+5]*(hi.y+gs[cb+5]) +
                os[cb+6]*(hi.z+gs[cb+6]) + os[cb+7]*(hi.w+gs[cb+7]);
      }
    }
  }

  if (FUSE) {
    // dots (f32-accurate); small stores, no barrier depends on them
    pp += __shfl_xor(pp, 16, 64);
    pp += __shfl_xor(pp, 32, 64);
    if (lg == 0 && vrow) dots[(size_t)b * MKJ + grow] = pp;
  }

  float b3v[2] = {ab3[0], cb3[0]};
  float* outs[2] = {outA, outQ};

  for (int h = 0; h < 2; ++h) {
    // ======== layer 1: 8 KB/nt weight tiles through LDS dbuf ========
    const char* wf1b = (const char*)wf1 + (size_t)h * 57344;
    {
      const uint4* src = (const uint4*)wf1b;     // nt = 0
      WB[0][tid] = src[tid];
      WB[0][tid + 256] = src[tid + 256];
    }
    int cur = 0;
    __syncthreads();
    for (int nt = 0; nt < NT1; ++nt) {
      uint4 s0, s1;
      if (nt < NT1 - 1) {
        const uint4* src = (const uint4*)(wf1b + (size_t)(nt + 1) * 8192);
        s0 = src[tid];
        s1 = src[tid + 256];
      }
      int n = nt * 16 + ln;
      float g = G1s[h * 112 + n];
      f32x4 acc = {g, g, g, g};
      #pragma unroll
      for (int ks = 0; ks < K1S; ++ks) {
        short8 bw = *(const short8*)&WB[cur][ks * 64 + lane];
        acc = __builtin_amdgcn_mfma_f32_16x16x32_bf16(a1[ks], bw, acc, 0, 0, 0);
      }
      if (n < DD) {
        #pragma unroll
        for (int r = 0; r < 4; ++r)
          H1[(w * 16 + lg * 4 + r) * H1S + n] = f2bf(fast_tanh(acc[r]));
      }
      if (nt < NT1 - 1) {
        WB[cur ^ 1][tid] = s0;
        WB[cur ^ 1][tid + 256] = s1;
        cur ^= 1;
      }
      __syncthreads();
    }

    // a2 fragments from own wave's H1 rows; zero K-pad cols (>=100) in-register
    short8 a2[4];
    #pragma unroll
    for (int ks = 0; ks < K2S; ++ks)
      a2[ks] = *(const short8*)&H1[myrow * H1S + ks * 32 + lg * 8];
    {
      union { short8 s; unsigned short us[8]; } m; m.s = a2[3];
      int cb = 96 + lg * 8;
      #pragma unroll
      for (int q = 0; q < 8; ++q) if (cb + q >= DD) m.us[q] = 0;
      a2[3] = m.s;
    }

    // ======== layer 2+3: 4 KB/nt weight tiles through LDS dbuf ========
    const char* wf2b = (const char*)wf2 + (size_t)h * 28672;
    WB[0][tid] = ((const uint4*)wf2b)[tid];    // nt = 0, 16-B stride
    cur = 0;
    __syncthreads();
    float part[4] = {0.f, 0.f, 0.f, 0.f};
    for (int nt = 0; nt < NT2; ++nt) {
      uint4 s0;
      if (nt < NT2 - 1)
        s0 = ((const uint4*)(wf2b + (size_t)(nt + 1) * 4096))[tid];
      f32x4 acc = {0.f, 0.f, 0.f, 0.f};
      #pragma unroll
      for (int ks = 0; ks < K2S; ++ks) {
        short8 bw = *(const short8*)&WB[cur][ks * 64 + lane];
        acc = __builtin_amdgcn_mfma_f32_16x16x32_bf16(a2[ks], bw, acc, 0, 0, 0);
      }
      int n = nt * 16 + ln;
      float b2v = b2s[h * 112 + n];
      float w3v = w3s[h * 112 + n];
      #pragma unroll
      for (int r = 0; r < 4; ++r)
        part[r] += fast_tanh(acc[r] + b2v) * w3v;
      if (nt < NT2 - 1) {
        WB[cur ^ 1][tid] = s0;
        cur ^= 1;
      }
      __syncthreads();
    }
    #pragma unroll
    for (int r = 0; r < 4; ++r) {
      float s = part[r];
      s += __shfl_xor(s, 1, 64); s += __shfl_xor(s, 2, 64);
      s += __shfl_xor(s, 4, 64); s += __shfl_xor(s, 8, 64);
      if (ln == 0) {
        int row = x * 64 + w * 16 + lg * 4 + r;
        if (row < MKJ) outs[h][(size_t)b * MKJ + row] = fast_sigmoid(s + b3v[h]);
      }
    }
    __syncthreads();
  }

  // ======== FUSE epilogue: dense NG store, LAST thing (stores drain at exit) ========
  if (FUSE) {
    // re-stage node bf16 into H1 (XOR-swizzled 16-B granules); H1 dead after head 1
    #pragma unroll
    for (int ks = 0; ks < 4; ++ks) {
      int col = (ks * 32 + lg * 8) ^ ((myrow & 7) << 3);
      *(short8*)&H1[myrow * H1S + col] = a1[ks];
    }
    __syncthreads();

    // dense NG: 64 rows x 400B contiguous slab, every sector written once
    const size_t ngbase = ((size_t)b * MKJ + (size_t)x * 64) * DD;
    for (int q = tid; q < 1600; q += 256) {
      int fidx = q * 4;
      int row = fidx / DD;          // 0..63 (100 % 4 == 0 -> no row crossing)
      int col = fidx - row * DD;
      if (x * 64 + row < MKJ) {
        int sc = ((col & ~7) ^ ((row & 7) << 3)) + (col & 7);
        unsigned long long d = *(const unsigned long long*)&H1[row * H1S + sc];
        f32x4 t;
        #pragma unroll
        for (int e = 0; e < 4; ++e) {
          unsigned u = (unsigned)((d >> (16 * e)) & 0xFFFFull) << 16;
          float v; __builtin_memcpy(&v, &u, 4);
          t[e] = v + gs[col + e];
        }
        __builtin_nontemporal_store(t, (f32x4*)(outNG + ngbase + fidx));
      }
    }
    // no barrier: stores drain at wave exit
  }
}

// ---------------- fallback rewards (non-fused path; full softmax inside) ----------------
__global__ __launch_bounds__(1024) void k_rewards(
    const float* __restrict__ nemb, const float* __restrict__ oemb,
    const float* __restrict__ gemb,
    const int* __restrict__ eadj, const int* __restrict__ nodes,
    float* __restrict__ outDR, float* __restrict__ outNG) {
  __shared__ float dots[MKJ];
  __shared__ float red[16];
  int b = blockIdx.x;
  int tid = threadIdx.x;
  int lane = tid & 63, w = tid >> 6;
  int d1 = lane + 64;
  float o0 = oemb[b * DD + lane];
  float g0 = gemb[b * DD + lane];
  float o1 = (d1 < DD) ? oemb[b * DD + d1] : 0.f;
  float g1 = (d1 < DD) ? gemb[b * DD + d1] : 0.f;
  for (int j = w; j < MKJ; j += 16) {
    int m = j / KADJ, kk = j - m * KADJ;
    int v = nodes[b * MM + m];
    int nid = eadj[v * KADJ + kk];
    const float* nr = nemb + (size_t)nid * DD;
    float s0 = g0 + nr[lane];
    float s1 = (d1 < DD) ? (g1 + nr[d1]) : 0.f;
    float* ngr = outNG + ((long long)b * MKJ + j) * DD;
    ngr[lane] = s0;
    if (d1 < DD) ngr[d1] = s1;
    float p = o0 * s0 + o1 * s1;
    p += __shfl_xor(p, 1, 64); p += __shfl_xor(p, 2, 64); p += __shfl_xor(p, 4, 64);
    p += __shfl_xor(p, 8, 64); p += __shfl_xor(p, 16, 64); p += __shfl_xor(p, 32, 64);
    if (lane == 0) dots[j] = p;
  }
  __syncthreads();
  float mx = -1e30f;
  for (int j = tid; j < MKJ; j += 1024) mx = fmaxf(mx, dots[j]);
  for (int off = 32; off; off >>= 1) mx = fmaxf(mx, __shfl_xor(mx, off, 64));
  if (lane == 0) red[w] = mx;
  __syncthreads();
  mx = red[0];
  #pragma unroll
  for (int i = 1; i < 16; ++i) mx = fmaxf(mx, red[i]);
  float se = 0.f;
  for (int j = tid; j < MKJ; j += 1024) se += __expf(dots[j] - mx);
  for (int off = 32; off; off >>= 1) se += __shfl_xor(se, off, 64);
  __syncthreads();
  if (lane == 0) red[w] = se;
  __syncthreads();
  se = 0.f;
  #pragma unroll
  for (int i = 0; i < 16; ++i) se += red[i];
  float inv = 1.f / se;
  for (int j = tid; j < MKJ; j += 1024) outDR[b * MKJ + j] = __expf(dots[j] - mx) * inv;
}

extern "C" void kernel_launch(void* const* d_in, const int* in_sizes, int n_in,
                              void* d_out, int out_size, void* d_ws, size_t ws_size,
                              hipStream_t stream) {
  const float* nemb = (const float*)d_in[0];
  const float* remb = (const float*)d_in[1];
  const float* oemb = (const float*)d_in[2];
  const float* gemb = (const float*)d_in[3];
  const float* aw1 = (const float*)d_in[4];
  const float* ab1 = (const float*)d_in[5];
  const float* aw2 = (const float*)d_in[6];
  const float* ab2 = (const float*)d_in[7];
  const float* aw3 = (const float*)d_in[8];
  const float* ab3 = (const float*)d_in[9];
  const float* cw1 = (const float*)d_in[10];
  const float* cb1 = (const float*)d_in[11];
  const float* cw2 = (const float*)d_in[12];
  const float* cb2 = (const float*)d_in[13];
  const float* cw3 = (const float*)d_in[14];
  const float* cb3 = (const float*)d_in[15];
  const int* eadj = (const int*)d_in[16];
  const int* radj = (const int*)d_in[17];
  const int* nodes = (const int*)d_in[18];

  float* out = (float*)d_out;
  float* outA = out;
  float* outQ = out + ROWS;
  float* outDR = out + 2 * ROWS;
  float* outNG = out + 3 * ROWS;

  // scratch: wf1 114,688 B | wf2 57,344 B | G1 212,992 B = 385,024 B
  const size_t need = 385024;
  bool fuse = ws_size >= need;
  char* scratch = (char*)d_ws;
  if (!fuse) {
    scratch = (char*)(out + ((size_t)3 * ROWS + (size_t)ROWS * DD - need / 4));
  }
  short* wf1 = (short*)scratch;
  short* wf2 = (short*)(scratch + 114688);
  float* G1 = (float*)(scratch + 172032);

  k_prep<<<544, 256, 0, stream>>>(gemb, aw1, ab1, cw1, cb1, aw2, cw2, wf1, wf2, G1);
  if (fuse) {
    k_all<true><<<4096, 256, 0, stream>>>(nemb, remb, oemb, gemb, eadj, radj, nodes,
                                          wf1, wf2, G1, ab2, cb2, aw3, ab3, cw3, cb3,
                                          outA, outQ, outDR, outNG);
    k_soft<<<BB, 256, 0, stream>>>(outDR);
  } else {
    k_all<false><<<4096, 256, 0, stream>>>(nemb, remb, oemb, gemb, eadj, radj, nodes,
                                           wf1, wf2, G1, ab2, cb2, aw3, ab3, cw3, cb3,
                                           outA, outQ, outDR, outNG);
    k_rewards<<<BB, 1024, 0, stream>>>(nemb, oemb, gemb, eadj, nodes, outDR, outNG);
  }
}